// Round 1
// baseline (1054.937 us; speedup 1.0000x reference)
//
#include <hip/hip_runtime.h>
#include <hip/hip_bf16.h>

#define NN 384
#define MM 32
#define KK 32

typedef __attribute__((ext_vector_type(8))) __bf16 bf16x8;
typedef __attribute__((ext_vector_type(4))) __bf16 bf16x4;
typedef __attribute__((ext_vector_type(4))) float f32x4;

__device__ __forceinline__ void split8(const float* v, bf16x8& hi, bf16x8& lo) {
#pragma unroll
    for (int t = 0; t < 8; ++t) {
        float f = v[t];
        __bf16 h = (__bf16)f;
        hi[t] = h;
        lo[t] = (__bf16)(f - (float)h);
    }
}

__device__ __forceinline__ void split4(const float* v, bf16x4& hi, bf16x4& lo) {
#pragma unroll
    for (int t = 0; t < 4; ++t) {
        float f = v[t];
        __bf16 h = (__bf16)f;
        hi[t] = h;
        lo[t] = (__bf16)(f - (float)h);
    }
}

// One wave (64 lanes) handles one (i,j) pair. S^T is computed DIRECTLY via
// swapped-operand MFMA (S^T = K*Q^T, same fragment data as Q*K^T), so softmax
// runs in registers with a 4-lane cross-quad shuffle reduce — no S LDS
// round-trip and no block barriers (all LDS is wave-private).
__global__ __launch_bounds__(256) void attn_pair_kernel(
    const float* __restrict__ x1,
    const float* __restrict__ mask,
    float* __restrict__ out)
{
    // per-wave LDS: P hi/lo bf16 (pitch 40)
    __shared__ __align__(16) __bf16 sPhi[4][32 * 40];
    __shared__ __align__(16) __bf16 sPlo[4][32 * 40];

    const int tid  = threadIdx.x;
    const int w    = tid >> 6;     // wave id in block
    const int l    = tid & 63;     // lane
    const int m16  = l & 15;
    const int quad = l >> 4;

    const unsigned p = blockIdx.x * 4u + (unsigned)w;   // pair index = i*384 + j
    const unsigned i = p / NN;
    const unsigned j = p - i * NN;

    const float* Q  = x1 + (size_t)j * (MM * KK);   // query == value tile
    const float* Kt = x1 + (size_t)i * (MM * KK);   // key tile

    // ---- issue dropout-mask loads FIRST: the only HBM-latency read in the
    //      chain; hides ~600-900 cy under QK^T + softmax.
    //      Fragment (aa,bb): row a=aa*16+m16, cols bb*16+quad*4 .. +3
    const float* mbase = mask + (size_t)p * (MM * MM);
    f32x4 mk[2][2];
#pragma unroll
    for (int aa = 0; aa < 2; ++aa)
#pragma unroll
        for (int bb = 0; bb < 2; ++bb)
            mk[aa][bb] = *(const f32x4*)(mbase + (aa * 16 + m16) * MM + bb * 16 + quad * 4);

    // ---- Q/K row fragments (identical layout serves as A or B operand) ----
    bf16x8 aQh[2], aQl[2], bKh[2], bKl[2];
#pragma unroll
    for (int h = 0; h < 2; ++h) {
        const int row = h * 16 + m16;
        float qbuf[8], kbuf[8];
        *(float4*)&qbuf[0] = *(const float4*)(Q  + row * KK + quad * 8);
        *(float4*)&qbuf[4] = *(const float4*)(Q  + row * KK + quad * 8 + 4);
        *(float4*)&kbuf[0] = *(const float4*)(Kt + row * KK + quad * 8);
        *(float4*)&kbuf[4] = *(const float4*)(Kt + row * KK + quad * 8 + 4);
        split8(qbuf, aQh[h], aQl[h]);
        split8(kbuf, bKh[h], bKl[h]);
    }

    // ---- S^T directly: ST[bb][aa] = K * Q^T (swapped operands) ----
    // C/D layout => lane holds S[a = aa*16+m16][b = bb*16+quad*4+r], r=0..3
    f32x4 ST[2][2];
#pragma unroll
    for (int bb = 0; bb < 2; ++bb)
#pragma unroll
        for (int aa = 0; aa < 2; ++aa) {
            f32x4 c = {0.f, 0.f, 0.f, 0.f};
            c = __builtin_amdgcn_mfma_f32_16x16x32_bf16(bKl[bb], aQh[aa], c, 0, 0, 0);
            c = __builtin_amdgcn_mfma_f32_16x16x32_bf16(bKh[bb], aQl[aa], c, 0, 0, 0);
            c = __builtin_amdgcn_mfma_f32_16x16x32_bf16(bKh[bb], aQh[aa], c, 0, 0, 0);
            ST[bb][aa] = c;
        }

    // ---- register softmax over b: column a's 32 values live in the 4 lanes
    //      {quad 0..3, same m16}, 8 each -> local reduce + shfl_xor(16,32)
    float pv[2][2][4];
#pragma unroll
    for (int aa = 0; aa < 2; ++aa) {
        float mx = ST[0][aa][0];
#pragma unroll
        for (int bb = 0; bb < 2; ++bb)
#pragma unroll
            for (int r = 0; r < 4; ++r) mx = fmaxf(mx, ST[bb][aa][r]);
        mx = fmaxf(mx, __shfl_xor(mx, 16, 64));
        mx = fmaxf(mx, __shfl_xor(mx, 32, 64));

        float sum = 0.f;
#pragma unroll
        for (int bb = 0; bb < 2; ++bb)
#pragma unroll
            for (int r = 0; r < 4; ++r) {
                float e = __expf(ST[bb][aa][r] - mx);
                pv[aa][bb][r] = e;
                sum += e;
            }
        sum += __shfl_xor(sum, 16, 64);
        sum += __shfl_xor(sum, 32, 64);
        const float rinv = 1.0f / sum;
#pragma unroll
        for (int bb = 0; bb < 2; ++bb)
#pragma unroll
            for (int r = 0; r < 4; ++r)
                pv[aa][bb][r] *= rinv * mk[aa][bb][r];
    }

    // ---- write P (bf16 hi/lo) to wave-private LDS in A-fragment row-major ----
    // row a = aa*16+m16 (pitch 40), cols b = bb*16+quad*4 .. +3
#pragma unroll
    for (int aa = 0; aa < 2; ++aa)
#pragma unroll
        for (int bb = 0; bb < 2; ++bb) {
            bf16x4 h4, l4;
            split4(pv[aa][bb], h4, l4);
            const int off = (aa * 16 + m16) * 40 + bb * 16 + quad * 4;
            *(bf16x4*)&sPhi[w][off] = h4;
            *(bf16x4*)&sPlo[w][off] = l4;
        }

    // ---- issue V column loads while the LDS writes drain (L1/L2-hot) ----
    float vbuf[2][8];
#pragma unroll
    for (int h = 0; h < 2; ++h) {
        const float* vp = Q + (quad * 8) * KK + (h * 16 + m16);
#pragma unroll
        for (int jj = 0; jj < 8; ++jj) vbuf[h][jj] = vp[jj * KK];
    }

    // wave-private LDS exchange: same-wave DS ops execute in order; wait for
    // the writes to complete, no inter-wave barrier needed.
    asm volatile("s_waitcnt lgkmcnt(0)" ::: "memory");

    // ---- O = P * V : A[m=a][k=b]=P, B[k=b][n=kout]=Q[b][kout] ----
    bf16x8 aPh[2], aPl[2], bVh[2], bVl[2];
#pragma unroll
    for (int h = 0; h < 2; ++h) {
        aPh[h] = *(const bf16x8*)&sPhi[w][(h * 16 + m16) * 40 + quad * 8];
        aPl[h] = *(const bf16x8*)&sPlo[w][(h * 16 + m16) * 40 + quad * 8];
        split8(vbuf[h], bVh[h], bVl[h]);
    }

    f32x4 O[2][2];
#pragma unroll
    for (int ma = 0; ma < 2; ++ma)
#pragma unroll
        for (int nk = 0; nk < 2; ++nk) {
            f32x4 c = {0.f, 0.f, 0.f, 0.f};
            c = __builtin_amdgcn_mfma_f32_16x16x32_bf16(aPl[ma], bVh[nk], c, 0, 0, 0);
            c = __builtin_amdgcn_mfma_f32_16x16x32_bf16(aPh[ma], bVl[nk], c, 0, 0, 0);
            c = __builtin_amdgcn_mfma_f32_16x16x32_bf16(aPh[ma], bVh[nk], c, 0, 0, 0);
            O[ma][nk] = c;
        }

    float* obase = out + (size_t)p * (MM * KK);
#pragma unroll
    for (int ma = 0; ma < 2; ++ma)
#pragma unroll
        for (int nk = 0; nk < 2; ++nk) {
            const int col = nk * 16 + m16;
            const int r0  = ma * 16 + quad * 4;
#pragma unroll
            for (int rr = 0; rr < 4; ++rr)
                obase[(r0 + rr) * KK + col] = O[ma][nk][rr];
        }
}

extern "C" void kernel_launch(void* const* d_in, const int* in_sizes, int n_in,
                              void* d_out, int out_size, void* d_ws, size_t ws_size,
                              hipStream_t stream) {
    const float* x1   = (const float*)d_in[0];
    const float* mask = (const float*)d_in[1];
    float* out = (float*)d_out;
    const int pairs = NN * NN;          // 147456
    dim3 grid(pairs / 4), block(256);   // 4 waves/block, 1 pair/wave
    attn_pair_kernel<<<grid, block, 0, stream>>>(x1, mask, out);
}

// Round 2
// 1017.304 us; speedup vs baseline: 1.0370x; 1.0370x over previous
//
#include <hip/hip_runtime.h>
#include <hip/hip_bf16.h>

#define NN 384
#define MM 32
#define KK 32
#define TILE (MM * KK)   // 1024 elements per (m,k) tile

typedef __attribute__((ext_vector_type(8))) __bf16 bf16x8;
typedef __attribute__((ext_vector_type(4))) __bf16 bf16x4;
typedef __attribute__((ext_vector_type(4))) float f32x4;

__device__ __forceinline__ void split8(const float* v, bf16x8& hi, bf16x8& lo) {
#pragma unroll
    for (int t = 0; t < 8; ++t) {
        float f = v[t];
        __bf16 h = (__bf16)f;
        hi[t] = h;
        lo[t] = (__bf16)(f - (float)h);
    }
}

// ---- prologue: pre-split x1 into bf16 hi/lo, row-major and transposed ----
// xhi/xlo: [tile][r][c] (row-major, serves Q/K row fragments)
// xthi/xtlo: [tile][c][r] (transposed, serves V column fragments)
__global__ __launch_bounds__(256) void presplit_kernel(
    const float* __restrict__ x1,
    __bf16* __restrict__ xhi,  __bf16* __restrict__ xlo,
    __bf16* __restrict__ xthi, __bf16* __restrict__ xtlo)
{
    const int g  = blockIdx.x * 256 + threadIdx.x;   // 0..98303
    const int e0 = g * 4;                            // 4 consecutive elements
    const int tile   = e0 >> 10;
    const int within = e0 & 1023;
    const int r  = within >> 5;
    const int c0 = within & 31;

    float4 v = *(const float4*)(x1 + e0);
    float f[4] = {v.x, v.y, v.z, v.w};
    bf16x4 h4, l4;
#pragma unroll
    for (int t = 0; t < 4; ++t) {
        __bf16 h = (__bf16)f[t];
        h4[t] = h;
        l4[t] = (__bf16)(f[t] - (float)h);
    }
    *(bf16x4*)(xhi + e0) = h4;
    *(bf16x4*)(xlo + e0) = l4;
#pragma unroll
    for (int t = 0; t < 4; ++t) {
        const int to = tile * TILE + (c0 + t) * MM + r;
        xthi[to] = h4[t];
        xtlo[to] = l4[t];
    }
}

// One wave (64 lanes) handles one (i,j) pair. Fully LDS-free:
//  - S^T computed directly via swapped-operand MFMA (register softmax)
//  - P goes straight from softmax registers into the O-MFMA A operand via a
//    sigma-permuted k relabeling; V's B-fragment is gathered in the same
//    sigma order. sigma(quad,jj) = quad*4+jj (jj<4) / 16+quad*4+jj-4 (jj>=4).
template<bool PRESPLIT>
__global__ __launch_bounds__(256) void attn_pair_kernel(
    const float* __restrict__ x1,
    const __bf16* __restrict__ xhi,  const __bf16* __restrict__ xlo,
    const __bf16* __restrict__ xthi, const __bf16* __restrict__ xtlo,
    const float* __restrict__ mask,
    float* __restrict__ out)
{
    const int tid  = threadIdx.x;
    const int w    = tid >> 6;     // wave id in block
    const int l    = tid & 63;     // lane
    const int m16  = l & 15;
    const int quad = l >> 4;

    const unsigned p = blockIdx.x * 4u + (unsigned)w;   // pair index = i*384 + j
    const unsigned i = p / NN;
    const unsigned j = p - i * NN;

    // ---- issue dropout-mask loads FIRST (only HBM-latency read) ----
    const float* mbase = mask + (size_t)p * (MM * MM);
    f32x4 mk[2][2];
#pragma unroll
    for (int aa = 0; aa < 2; ++aa)
#pragma unroll
        for (int bb = 0; bb < 2; ++bb)
            mk[aa][bb] = *(const f32x4*)(mbase + (aa * 16 + m16) * MM + bb * 16 + quad * 4);

    // ---- Q/K row fragments (identical layout serves as A or B operand) ----
    bf16x8 aQh[2], aQl[2], bKh[2], bKl[2];
    if constexpr (PRESPLIT) {
        const __bf16* Qh = xhi + (size_t)j * TILE;
        const __bf16* Ql = xlo + (size_t)j * TILE;
        const __bf16* Kh = xhi + (size_t)i * TILE;
        const __bf16* Kl = xlo + (size_t)i * TILE;
#pragma unroll
        for (int h = 0; h < 2; ++h) {
            const int off = (h * 16 + m16) * KK + quad * 8;
            aQh[h] = *(const bf16x8*)(Qh + off);
            aQl[h] = *(const bf16x8*)(Ql + off);
            bKh[h] = *(const bf16x8*)(Kh + off);
            bKl[h] = *(const bf16x8*)(Kl + off);
        }
    } else {
        const float* Q  = x1 + (size_t)j * TILE;
        const float* Kt = x1 + (size_t)i * TILE;
#pragma unroll
        for (int h = 0; h < 2; ++h) {
            const int row = h * 16 + m16;
            float qbuf[8], kbuf[8];
            *(float4*)&qbuf[0] = *(const float4*)(Q  + row * KK + quad * 8);
            *(float4*)&qbuf[4] = *(const float4*)(Q  + row * KK + quad * 8 + 4);
            *(float4*)&kbuf[0] = *(const float4*)(Kt + row * KK + quad * 8);
            *(float4*)&kbuf[4] = *(const float4*)(Kt + row * KK + quad * 8 + 4);
            split8(qbuf, aQh[h], aQl[h]);
            split8(kbuf, bKh[h], bKl[h]);
        }
    }

    // ---- S^T directly: ST[bb][aa] = K * Q^T (swapped operands) ----
    // lane holds S[a = aa*16+m16][b = bb*16+quad*4+r], r=0..3
    f32x4 ST[2][2];
#pragma unroll
    for (int bb = 0; bb < 2; ++bb)
#pragma unroll
        for (int aa = 0; aa < 2; ++aa) {
            f32x4 c = {0.f, 0.f, 0.f, 0.f};
            c = __builtin_amdgcn_mfma_f32_16x16x32_bf16(bKl[bb], aQh[aa], c, 0, 0, 0);
            c = __builtin_amdgcn_mfma_f32_16x16x32_bf16(bKh[bb], aQl[aa], c, 0, 0, 0);
            c = __builtin_amdgcn_mfma_f32_16x16x32_bf16(bKh[bb], aQh[aa], c, 0, 0, 0);
            ST[bb][aa] = c;
        }

    // ---- register softmax over b (4-lane cross-quad reduce) + mask ----
    float pv[2][2][4];
#pragma unroll
    for (int aa = 0; aa < 2; ++aa) {
        float mx = ST[0][aa][0];
#pragma unroll
        for (int bb = 0; bb < 2; ++bb)
#pragma unroll
            for (int r = 0; r < 4; ++r) mx = fmaxf(mx, ST[bb][aa][r]);
        mx = fmaxf(mx, __shfl_xor(mx, 16, 64));
        mx = fmaxf(mx, __shfl_xor(mx, 32, 64));

        float sum = 0.f;
#pragma unroll
        for (int bb = 0; bb < 2; ++bb)
#pragma unroll
            for (int r = 0; r < 4; ++r) {
                float e = __expf(ST[bb][aa][r] - mx);
                pv[aa][bb][r] = e;
                sum += e;
            }
        sum += __shfl_xor(sum, 16, 64);
        sum += __shfl_xor(sum, 32, 64);
        const float rinv = 1.0f / sum;
#pragma unroll
        for (int bb = 0; bb < 2; ++bb)
#pragma unroll
            for (int r = 0; r < 4; ++r)
                pv[aa][bb][r] *= rinv * mk[aa][bb][r];
    }

    // ---- P as A-fragment directly (sigma-permuted k): no LDS, no shuffles ----
    // A_frag[ma] elems 0..3 = P[..][quad*4+r] (bb=0), 4..7 = P[..][16+quad*4+r]
    bf16x8 aPh[2], aPl[2];
#pragma unroll
    for (int ma = 0; ma < 2; ++ma) {
        float tmp[8];
#pragma unroll
        for (int r = 0; r < 4; ++r) { tmp[r] = pv[ma][0][r]; tmp[4 + r] = pv[ma][1][r]; }
        split8(tmp, aPh[ma], aPl[ma]);
    }

    // ---- V B-fragment in the same sigma order ----
    // lane needs V[quad*4+jj][n] (jj<4) and V[16+quad*4+jj-4][n], n = nk*16+m16
    bf16x8 bVh[2], bVl[2];
    if constexpr (PRESPLIT) {
        const __bf16* Th = xthi + (size_t)j * TILE;   // [c][r] transposed tile
        const __bf16* Tl = xtlo + (size_t)j * TILE;
#pragma unroll
        for (int nk = 0; nk < 2; ++nk) {
            const int base = (nk * 16 + m16) * MM + quad * 4;
            bf16x4 h0 = *(const bf16x4*)(Th + base);
            bf16x4 h1 = *(const bf16x4*)(Th + base + 16);
            bf16x4 l0 = *(const bf16x4*)(Tl + base);
            bf16x4 l1 = *(const bf16x4*)(Tl + base + 16);
            bf16x8 hv, lv;
#pragma unroll
            for (int t = 0; t < 4; ++t) {
                hv[t] = h0[t]; hv[4 + t] = h1[t];
                lv[t] = l0[t]; lv[4 + t] = l1[t];
            }
            bVh[nk] = hv; bVl[nk] = lv;
        }
    } else {
        const float* V = x1 + (size_t)j * TILE;
#pragma unroll
        for (int nk = 0; nk < 2; ++nk) {
            const int col = nk * 16 + m16;
            float vbuf[8];
#pragma unroll
            for (int jj = 0; jj < 4; ++jj) {
                vbuf[jj]     = V[(quad * 4 + jj) * KK + col];
                vbuf[4 + jj] = V[(16 + quad * 4 + jj) * KK + col];
            }
            split8(vbuf, bVh[nk], bVl[nk]);
        }
    }

    // ---- O = P * V ----
    f32x4 O[2][2];
#pragma unroll
    for (int ma = 0; ma < 2; ++ma)
#pragma unroll
        for (int nk = 0; nk < 2; ++nk) {
            f32x4 c = {0.f, 0.f, 0.f, 0.f};
            c = __builtin_amdgcn_mfma_f32_16x16x32_bf16(aPl[ma], bVh[nk], c, 0, 0, 0);
            c = __builtin_amdgcn_mfma_f32_16x16x32_bf16(aPh[ma], bVl[nk], c, 0, 0, 0);
            c = __builtin_amdgcn_mfma_f32_16x16x32_bf16(aPh[ma], bVh[nk], c, 0, 0, 0);
            O[ma][nk] = c;
        }

    float* obase = out + (size_t)p * (MM * KK);
#pragma unroll
    for (int ma = 0; ma < 2; ++ma)
#pragma unroll
        for (int nk = 0; nk < 2; ++nk) {
            const int col = nk * 16 + m16;
            const int r0  = ma * 16 + quad * 4;
#pragma unroll
            for (int rr = 0; rr < 4; ++rr)
                obase[(r0 + rr) * KK + col] = O[ma][nk][rr];
        }
}

extern "C" void kernel_launch(void* const* d_in, const int* in_sizes, int n_in,
                              void* d_out, int out_size, void* d_ws, size_t ws_size,
                              hipStream_t stream) {
    const float* x1   = (const float*)d_in[0];
    const float* mask = (const float*)d_in[1];
    float* out = (float*)d_out;
    const int pairs = NN * NN;          // 147456
    dim3 grid(pairs / 4), block(256);   // 4 waves/block, 1 pair/wave

    const size_t elems = (size_t)NN * TILE;          // 393216
    const size_t need  = elems * 2 * 4;              // 4 bf16 arrays = 3,145,728 B
    if (d_ws != nullptr && ws_size >= need) {
        __bf16* xhi  = (__bf16*)d_ws;
        __bf16* xlo  = xhi  + elems;
        __bf16* xthi = xlo  + elems;
        __bf16* xtlo = xthi + elems;
        presplit_kernel<<<dim3(elems / 4 / 256), block, 0, stream>>>(x1, xhi, xlo, xthi, xtlo);
        attn_pair_kernel<true><<<grid, block, 0, stream>>>(x1, xhi, xlo, xthi, xtlo, mask, out);
    } else {
        attn_pair_kernel<false><<<grid, block, 0, stream>>>(x1, nullptr, nullptr, nullptr, nullptr, mask, out);
    }
}